// Round 1
// 247.210 us; speedup vs baseline: 1.0271x; 1.0271x over previous
//
#include <hip/hip_runtime.h>
#include <hip/hip_bf16.h>

#define BB 32
#define HH 56
#define WW 56
#define CC 256
#define NPIX (BB*HH*WW)   // 100352
#define EPS 1e-5f

typedef short bf16x8 __attribute__((ext_vector_type(8)));   // 8 bf16 = 4 VGPRs
typedef float f32x4  __attribute__((ext_vector_type(4)));

__device__ __forceinline__ unsigned short f2bf(float f) {
    __hip_bfloat16 h = __float2bfloat16(f);
    return *reinterpret_cast<unsigned short*>(&h);
}

// ws layout:
//   float stats[512]   : byte 0      (sum[256], sumsq[256])
//   float ss[512]      : byte 2048   (scale[256], shift[256])
//   bf16  y[B*H*W*256] : byte 4096   (51.4 MB)

__global__ void k0_zero(float* stats) { stats[threadIdx.x] = 0.f; }

// Grouped conv via bf16 MFMA. Block: one group-pair (16 out-ch), one 8-row
// band, one batch image. K packed [g0 taps + pad][g1 taps + pad] = 160
// -> 5 x mfma_f32_16x16x32_bf16 with block-diagonal operand.
// vs previous version:
//  * weights as the A operand, pixels as B. A/B frags have identical lane
//    mapping (idx=lane&15, K-octet=lane>>4) so LDS addressing is unchanged,
//    but C flips: lane holds 4 CONSECUTIVE CHANNELS of one pixel ->
//    one ushort4 (8B) y-store per col-tile (7 stores/thread, was 28 x 2B),
//    and stats reduce via 16-lane shfl_xor (64 LDS atomics/block, was 512).
//  * no wb LDS staging: 5 A-frags loaded straight from global (288KB
//    weight array is L1/L2-resident broadcast). LDS 33.3KB -> 28KB ->
//    5 blocks/CU (62% occupancy cap, was 4 blocks / 50%).
// Per-pixel LDS stride stays 24 shorts (48B): 2-way bank aliasing = free.
__global__ __launch_bounds__(256, 5) void k1_conv(
    const float* __restrict__ x, const float* __restrict__ wgt,
    __hip_bfloat16* __restrict__ y, float* __restrict__ stats)
{
    __shared__ unsigned short xt[10*58*24];   // bf16 tile, padded stride (27.8 KB)
    __shared__ float bsum[16], bsq[16];

    const int gp = blockIdx.x;      // group pair 0..15 (channels gp*16..+16)
    const int hb = blockIdx.y;      // 8-row band 0..6
    const int b  = blockIdx.z;
    const int t  = threadIdx.x;
    const int h0 = hb * 8;

    if (t < 16) { bsum[t] = 0.f; bsq[t] = 0.f; }

    // ---- stage x tile (rows h0-1..h0+8, cols -1..56, 16 ch), fully unrolled:
    // all global loads issued before any conversion (batched vmcnt).
    float4 v[10];
    int    off[10];
    #pragma unroll
    for (int j = 0; j < 10; ++j) {
        const int i   = j*256 + t;        // < 2320 valid (only j=9 partial)
        const int ci4 = i & 3;
        const int cq  = i >> 2;
        const int row = cq / 58;          // const divisor -> magic mul
        const int col = cq - row*58;
        const int hh  = h0 - 1 + row;
        const int wc  = col - 1;
        off[j] = (row*58 + col)*24 + ci4*4;
        v[j] = make_float4(0.f, 0.f, 0.f, 0.f);
        if (i < 2320 && (unsigned)hh < HH && (unsigned)wc < WW)
            v[j] = *(const float4*)(x + (((size_t)(b*HH + hh)*WW + wc)*CC + gp*16 + ci4*4));
    }
    #pragma unroll
    for (int j = 0; j < 10; ++j) {
        if (j*256 + t < 2320) {
            ushort4 s;
            s.x = f2bf(v[j].x); s.y = f2bf(v[j].y);
            s.z = f2bf(v[j].z); s.w = f2bf(v[j].w);
            *(ushort4*)(xt + off[j]) = s;
        }
    }

    const int lane = t & 63;
    const int rp   = t >> 6;              // wave id = row-pair 0..3
    const int n    = lane & 15;           // A row (local out-ch)
    const int q    = lane >> 4;           // K-octet

    // ---- A-fragments (weights) straight from global: octet o = one tap of
    // one group-half, elements = the 8 in-ch of that tap (stride 1KB, L1-hit).
    bf16x8 wfrag[5];
    #pragma unroll
    for (int s = 0; s < 5; ++s) {
        const int o   = s*4 + q;          // octet 0..19
        const int g   = (o >= 10);
        const int tap = o - g*10;
        bf16x8 f = {0,0,0,0,0,0,0,0};
        if (tap < 9 && (n >> 3) == g) {
            #pragma unroll
            for (int e = 0; e < 8; ++e)
                f[e] = (short)f2bf(wgt[(tap*8 + e)*CC + gp*16 + n]);
        }
        wfrag[s] = f;
    }

    __syncthreads();

    const int m    = lane & 15;           // B col (pixel in 2x8 tile)
    const int rowr = rp*2 + (m >> 3);     // tile row of pixel (0..7)
    const int colb = m & 7;               // tile col within 8-col tile

    // B-fragment LDS offsets per K-step (lane octet -> tap,g) -- unchanged
    int aoff[5];
    #pragma unroll
    for (int s = 0; s < 5; ++s) {
        int o  = s*4 + q;
        int g  = (o >= 10);
        int tp = o - g*10;
        if (tp == 9) tp = 0;              // pad octet: A is zero, addr dontcare
        int dh = tp / 3, dw = tp - dh*3;
        aoff[s] = ((rowr + dh)*58 + colb + dw)*24 + g*8;
    }

    const int h = h0 + rowr;
    const size_t pixbase = ((size_t)(b*HH + h))*WW;
    float lsum[4] = {0.f, 0.f, 0.f, 0.f};
    float lsq[4]  = {0.f, 0.f, 0.f, 0.f};

    #pragma unroll 2
    for (int ct = 0; ct < 7; ++ct) {      // 7 col-tiles of 8 pixels
        f32x4 acc = {0.f, 0.f, 0.f, 0.f};
        #pragma unroll
        for (int s = 0; s < 5; ++s) {
            bf16x8 af = *(const bf16x8*)(xt + aoff[s] + ct*192);
            acc = __builtin_amdgcn_mfma_f32_16x16x32_bf16(wfrag[s], af, acc, 0, 0, 0);
        }
        // lane holds channels gp*16 + q*4 + 0..3 of pixel (h, ct*8+colb)
        ushort4 st;
        st.x = f2bf(acc[0]); st.y = f2bf(acc[1]);
        st.z = f2bf(acc[2]); st.w = f2bf(acc[3]);
        *(ushort4*)(y + (pixbase + ct*8 + colb)*CC + gp*16 + q*4) = st;
        #pragma unroll
        for (int i = 0; i < 4; ++i) {
            lsum[i] += acc[i];
            lsq[i]  += acc[i]*acc[i];
        }
    }

    // reduce over the 16 lanes sharing this channel quad (same q)
    #pragma unroll
    for (int d = 8; d >= 1; d >>= 1) {
        #pragma unroll
        for (int i = 0; i < 4; ++i) {
            lsum[i] += __shfl_xor(lsum[i], d);
            lsq[i]  += __shfl_xor(lsq[i],  d);
        }
    }
    if (m == 0) {
        #pragma unroll
        for (int i = 0; i < 4; ++i) {
            atomicAdd(&bsum[q*4 + i], lsum[i]);
            atomicAdd(&bsq[q*4 + i],  lsq[i]);
        }
    }
    __syncthreads();
    if (t < 16) {
        atomicAdd(&stats[gp*16 + t],       bsum[t]);
        atomicAdd(&stats[256 + gp*16 + t], bsq[t]);
    }
}

__global__ void k2_finalize(const float* __restrict__ stats,
                            const float* __restrict__ gamma,
                            const float* __restrict__ beta,
                            float* __restrict__ ss)
{
    int c = threadIdx.x;
    float inv_n = 1.f / (float)NPIX;
    float mean = stats[c] * inv_n;
    float var  = stats[256 + c] * inv_n - mean * mean;
    float scale = gamma[c] * rsqrtf(var + EPS);
    ss[c]       = scale;
    ss[256 + c] = beta[c] - mean * scale;   // conv bias cancels under BN
}

// Normalize+ReLU. Fixed channel-octet per thread (scale/shift in regs, no
// LDS). 4 rounds per thread, 3136 blocks -> many independent memory streams.
__global__ __launch_bounds__(256) void k3_norm(
    const __hip_bfloat16* __restrict__ y, const float* __restrict__ ss,
    float* __restrict__ out)
{
    const int t   = threadIdx.x;
    const int oct = t & 31;               // channel octet
    const int pr  = t >> 5;               // pixel sub-index 0..7
    const int c0  = oct * 8;

    float4 sc0 = *(const float4*)(ss + c0);
    float4 sc1 = *(const float4*)(ss + c0 + 4);
    float4 sh0 = *(const float4*)(ss + 256 + c0);
    float4 sh1 = *(const float4*)(ss + 256 + c0 + 4);

    const uint4* yv = (const uint4*)y;
    float4* ov = (float4*)out;
    const int px0 = blockIdx.x * 32 + pr;

    uint4 d[4];
    #pragma unroll
    for (int i = 0; i < 4; ++i)
        d[i] = yv[(size_t)(px0 + i*8)*32 + oct];

    #pragma unroll
    for (int i = 0; i < 4; ++i) {
        const int px = px0 + i*8;
        float f0 = __uint_as_float((d[i].x & 0xffffu) << 16);
        float f1 = __uint_as_float(d[i].x & 0xffff0000u);
        float f2 = __uint_as_float((d[i].y & 0xffffu) << 16);
        float f3 = __uint_as_float(d[i].y & 0xffff0000u);
        float f4 = __uint_as_float((d[i].z & 0xffffu) << 16);
        float f5 = __uint_as_float(d[i].z & 0xffff0000u);
        float f6 = __uint_as_float((d[i].w & 0xffffu) << 16);
        float f7 = __uint_as_float(d[i].w & 0xffff0000u);

        float4 o0, o1;
        o0.x = fmaxf(0.f, f0 * sc0.x + sh0.x);
        o0.y = fmaxf(0.f, f1 * sc0.y + sh0.y);
        o0.z = fmaxf(0.f, f2 * sc0.z + sh0.z);
        o0.w = fmaxf(0.f, f3 * sc0.w + sh0.w);
        o1.x = fmaxf(0.f, f4 * sc1.x + sh1.x);
        o1.y = fmaxf(0.f, f5 * sc1.y + sh1.y);
        o1.z = fmaxf(0.f, f6 * sc1.z + sh1.z);
        o1.w = fmaxf(0.f, f7 * sc1.w + sh1.w);

        ov[(size_t)px*64 + oct*2]     = o0;
        ov[(size_t)px*64 + oct*2 + 1] = o1;
    }
}

extern "C" void kernel_launch(void* const* d_in, const int* in_sizes, int n_in,
                              void* d_out, int out_size, void* d_ws, size_t ws_size,
                              hipStream_t stream) {
    const float* x     = (const float*)d_in[0];
    const float* wgt   = (const float*)d_in[1];
    // d_in[2] = conv bias: cancels exactly under BN mean-subtraction -- unused
    const float* gamma = (const float*)d_in[3];
    const float* beta  = (const float*)d_in[4];
    float* out = (float*)d_out;

    float* stats = (float*)d_ws;                                 // 512 floats
    float* ss    = (float*)((char*)d_ws + 2048);                 // 512 floats
    __hip_bfloat16* y = (__hip_bfloat16*)((char*)d_ws + 4096);   // 25.69M bf16

    k0_zero<<<1, 512, 0, stream>>>(stats);
    k1_conv<<<dim3(16, 7, BB), 256, 0, stream>>>(x, wgt, y, stats);
    k2_finalize<<<1, 256, 0, stream>>>(stats, gamma, beta, ss);
    k3_norm<<<NPIX/32, 256, 0, stream>>>(y, ss, out);
}